// Round 4
// baseline (68.121 us; speedup 1.0000x reference)
//
#include <hip/hip_runtime.h>

// IMMLoss: B=32 groups, M=4 rows, D=196608 features, f32.
// loss = mean_b( wtout[b] * (mean K(st,st) + mean K(sr,sr) - 2*mean K(st,sr)) )
// K(x,y)_ij = exp(clip(-w[b]*sqrt(max(|x_i-y_j|^2,1e-12))/D, -1e6, 0))
// Single-wave blocks, barrier-free counted-vmcnt global_load_lds pipeline.

constexpr int NB = 32;        // groups
constexpr int MM = 4;         // rows per group (8 combined: 4 st + 4 sr)
constexpr int DD = 196608;    // feature dim
constexpr int D4 = DD / 4;    // 49152 float4 per row
constexpr int BPG = 48;       // blocks per group -> 1536 blocks = 6/CU exact
constexpr int NTHREADS = 64;  // ONE wave per block: no barriers needed
constexpr int CHUNK4 = D4 / BPG;   // 1024 float4 columns per block
constexpr int TB = 64;             // columns per stage (1 col per lane)
constexpr int NITER = CHUNK4 / TB; // 16
constexpr int NBUF = 3;            // 3 x 8KB LDS buffers, prefetch depth 2
constexpr int NACC = 36;           // 10 ss-tri + 10 rr-tri + 16 cross

__device__ __forceinline__ void gl_lds16(const float4* gsrc, float4* lds_dst) {
    __builtin_amdgcn_global_load_lds(
        (const __attribute__((address_space(1))) void*)gsrc,
        (__attribute__((address_space(3))) void*)lds_dst,
        16, 0, 0);
}

__global__ __launch_bounds__(NTHREADS) void mmd_partial_kernel(
    const float* __restrict__ st, const float* __restrict__ sr,
    float* __restrict__ partial)
{
    __shared__ float4 buf[NBUF][8][TB];   // 24 KiB

    const int b    = blockIdx.x / BPG;
    const int blk  = blockIdx.x % BPG;
    const int c0   = blk * CHUNK4;
    const int lane = threadIdx.x;         // 0..63

    const float4* stb = reinterpret_cast<const float4*>(st) + (size_t)b * MM * D4;
    const float4* srb = reinterpret_cast<const float4*>(sr) + (size_t)b * MM * D4;

    // Per-lane global source pointers, rows 0-3 = st, 4-7 = sr.
    const float4* srcp[8];
#pragma unroll
    for (int r = 0; r < 4; ++r) srcp[r]     = stb + (size_t)r * D4 + c0 + lane;
#pragma unroll
    for (int r = 0; r < 4; ++r) srcp[4 + r] = srb + (size_t)r * D4 + c0 + lane;

    // Stage s: 8 x (64 lanes x 16B = 1KB contiguous) -> buf[s % NBUF].
    // LDS dest is the wave-uniform row base; HW adds lane*16.
    auto stage = [&](int s) {
        const int cur = s % NBUF;
#pragma unroll
        for (int r = 0; r < 8; ++r)
            gl_lds16(srcp[r] + s * TB, &buf[cur][r][0]);
    };

    float acc[NACC];
#pragma unroll
    for (int k = 0; k < NACC; ++k) acc[k] = 0.0f;

    stage(0);
    stage(1);   // 16 loads in flight

#pragma unroll
    for (int it = 0; it < NITER; ++it) {
        // Wait only for the oldest stage (8 loads); keep the rest in flight.
        if (it == NITER - 1) asm volatile("s_waitcnt vmcnt(0)" ::: "memory");
        else                 asm volatile("s_waitcnt vmcnt(8)" ::: "memory");
        if (it + 2 < NITER) stage(it + 2);

        const int cur = it % NBUF;
        float4 x[8];
#pragma unroll
        for (int r = 0; r < 8; ++r) x[r] = buf[cur][r][lane];

        int k = 0;
#pragma unroll
        for (int i = 0; i < MM; ++i)
#pragma unroll
            for (int j = i; j < MM; ++j) {
                acc[k] += x[i].x * x[j].x + x[i].y * x[j].y +
                          x[i].z * x[j].z + x[i].w * x[j].w;
                ++k;
            }
#pragma unroll
        for (int i = 0; i < MM; ++i)
#pragma unroll
            for (int j = i; j < MM; ++j) {
                acc[k] += x[4+i].x * x[4+j].x + x[4+i].y * x[4+j].y +
                          x[4+i].z * x[4+j].z + x[4+i].w * x[4+j].w;
                ++k;
            }
#pragma unroll
        for (int i = 0; i < MM; ++i)
#pragma unroll
            for (int j = 0; j < MM; ++j) {
                acc[k] += x[i].x * x[4+j].x + x[i].y * x[4+j].y +
                          x[i].z * x[4+j].z + x[i].w * x[4+j].w;
                ++k;
            }
    }

    // 64-lane butterfly reduce; lane 0 writes the 36 block partials.
#pragma unroll
    for (int k = 0; k < NACC; ++k) {
        float v = acc[k];
        for (int off = 32; off > 0; off >>= 1) v += __shfl_down(v, off, 64);
        acc[k] = v;
    }
    if (lane == 0) {
        float* p = partial + (size_t)blockIdx.x * NACC;
#pragma unroll
        for (int k = 0; k < NACC; ++k) p[k] = acc[k];
    }
}

__global__ __launch_bounds__(1024) void mmd_final_kernel(
    const float* __restrict__ partial, const float* __restrict__ wt,
    const float* __restrict__ wtout, float* __restrict__ out)
{
    __shared__ float acc_s[NB][NACC];
    for (int p = threadIdx.x; p < NB * NACC; p += 1024) {
        const int b = p / NACC;
        const int k = p % NACC;
        float s = 0.0f;
        for (int blk = 0; blk < BPG; ++blk)
            s += partial[((size_t)b * BPG + blk) * NACC + k];
        acc_s[b][k] = s;
    }
    __syncthreads();

    __shared__ float lds[NB];
    const int b = threadIdx.x;
    if (b < NB) {
        const float* a = acc_s[b];
        float ss[MM][MM], rr[MM][MM], sg[MM][MM];
        {
            int k = 0;
            for (int i = 0; i < MM; ++i)
                for (int j = i; j < MM; ++j) { ss[i][j] = a[k]; ss[j][i] = a[k]; ++k; }
            for (int i = 0; i < MM; ++i)
                for (int j = i; j < MM; ++j) { rr[i][j] = a[k]; rr[j][i] = a[k]; ++k; }
            for (int i = 0; i < MM; ++i)
                for (int j = 0; j < MM; ++j) { sg[i][j] = a[k]; ++k; }
        }

        const float w    = wt[b];
        const float invD = 1.0f / (float)DD;  // sigma = 1
        auto kv = [&](float d2) -> float {
            d2 = fmaxf(d2, 1e-12f);
            float dist = sqrtf(d2) * invD;
            float e = -dist * w;
            e = fminf(fmaxf(e, -1e6f), 0.0f);
            return expf(e);
        };

        float mss = 0.0f, mrr = 0.0f, msr = 0.0f;
        for (int i = 0; i < MM; ++i) {
            for (int j = 0; j < MM; ++j) {
                mss += kv(ss[i][i] + ss[j][j] - 2.0f * ss[i][j]);
                mrr += kv(rr[i][i] + rr[j][j] - 2.0f * rr[i][j]);
                msr += kv(ss[i][i] + rr[j][j] - 2.0f * sg[i][j]);
            }
        }
        const float inv16 = 1.0f / 16.0f;
        float loss_raw = mss * inv16 + mrr * inv16 - 2.0f * (msr * inv16);
        lds[b] = wtout[b] * loss_raw;
    }
    __syncthreads();
    if (threadIdx.x == 0) {
        float s = 0.0f;
        for (int i = 0; i < NB; ++i) s += lds[i];
        out[0] = s / (float)NB;
    }
}

extern "C" void kernel_launch(void* const* d_in, const int* in_sizes, int n_in,
                              void* d_out, int out_size, void* d_ws, size_t ws_size,
                              hipStream_t stream) {
    const float* f_st  = (const float*)d_in[0];
    const float* f_sr  = (const float*)d_in[1];
    const float* wt    = (const float*)d_in[2];
    const float* wtout = (const float*)d_in[3];
    float* out     = (float*)d_out;
    float* partial = (float*)d_ws;   // NB*BPG*NACC floats = 221184 B

    mmd_partial_kernel<<<NB * BPG, NTHREADS, 0, stream>>>(f_st, f_sr, partial);
    mmd_final_kernel<<<1, 1024, 0, stream>>>(partial, wt, wtout, out);
}

// Round 5
// 43.208 us; speedup vs baseline: 1.5766x; 1.5766x over previous
//
#include <hip/hip_runtime.h>

// IMMLoss: B=32 groups, M=4 rows, D=196608 features, f32.
// loss = mean_b( wtout[b] * (mean K(st,st) + mean K(sr,sr) - 2*mean K(st,sr)) )
// Streaming Gram accumulation: multi-wave blocks, triple-buffered
// global_load_lds with counted vmcnt + raw s_barrier (no full drains).

constexpr int NB = 32;        // groups
constexpr int MM = 4;         // rows per group (8 combined: 4 st + 4 sr)
constexpr int DD = 196608;    // feature dim
constexpr int D4 = DD / 4;    // 49152 float4 per row
constexpr int BPG = 24;       // blocks per group -> 768 blocks = 3/CU exact
constexpr int NTHREADS = 256; // 4 waves
constexpr int TB = 128;       // columns per stage
constexpr int CHUNK4 = D4 / BPG;   // 2048 float4 columns per block
constexpr int NITER = CHUNK4 / TB; // 16
constexpr int NBUF = 3;            // 3 x 16KB LDS buffers, 2 stages in flight
constexpr int NPAIR = 18;          // pairs per thread (36 split across 2 sets)
constexpr int NACC = 36;

__device__ __forceinline__ void gl_lds16(const float4* gsrc, float4* lds_dst) {
    __builtin_amdgcn_global_load_lds(
        (const __attribute__((address_space(1))) void*)gsrc,
        (__attribute__((address_space(3))) void*)lds_dst,
        16, 0, 0);
}

__device__ __forceinline__ float dot4(const float4& a, const float4& b) {
    return a.x * b.x + a.y * b.y + a.z * b.z + a.w * b.w;
}

__global__ __launch_bounds__(NTHREADS) void mmd_partial_kernel(
    const float* __restrict__ st, const float* __restrict__ sr,
    float* __restrict__ partial)
{
    __shared__ float4 buf[NBUF][8][TB];   // 48 KiB
    __shared__ float red[4][NPAIR];

    const int b    = blockIdx.x / BPG;
    const int blk  = blockIdx.x % BPG;
    const int c0   = blk * CHUNK4;
    const int tid  = threadIdx.x;
    const int wave = tid >> 6;
    const int lane = tid & 63;
    const int col  = tid & (TB - 1);   // column within tile (2 threads/col)
    const int set  = wave >> 1;        // 0: ss+cross(i=0,1)  1: rr+cross(i=2,3)

    const float4* stb = reinterpret_cast<const float4*>(st) + (size_t)b * MM * D4;
    const float4* srb = reinterpret_cast<const float4*>(sr) + (size_t)b * MM * D4;

    // This wave stages rows r0, r0+1 (rows 0-3 = st, 4-7 = sr).
    const int r0 = 2 * wave;
    const float4* g0 = (r0 < 4 ? stb + (size_t)r0 * D4
                                : srb + (size_t)(r0 - 4) * D4) + c0 + lane;
    const float4* g1 = (r0 + 1 < 4 ? stb + (size_t)(r0 + 1) * D4
                                    : srb + (size_t)(r0 - 3) * D4) + c0 + lane;

    // Stage s: this wave issues 4 x (64 lanes x 16B = 1KB). LDS dest is the
    // wave-uniform row base; HW adds lane*16. vmcnt is per-wave.
    auto stage = [&](int s) {
        const int m   = s % NBUF;
        const int off = s * TB;
        gl_lds16(g0 + off,      &buf[m][r0][0]);
        gl_lds16(g0 + off + 64, &buf[m][r0][64]);
        gl_lds16(g1 + off,      &buf[m][r0 + 1][0]);
        gl_lds16(g1 + off + 64, &buf[m][r0 + 1][64]);
    };

    float acc[NPAIR];
#pragma unroll
    for (int k = 0; k < NPAIR; ++k) acc[k] = 0.0f;

    stage(0);
    stage(1);   // 2 stages (8 loads/wave) in flight

#pragma unroll
    for (int t = 0; t < NITER; ++t) {
        // My ds_reads of tile t-1 have sampled LDS -> safe for others to
        // overwrite the oldest buffer after the barrier.
        asm volatile("s_waitcnt lgkmcnt(0)" ::: "memory");
        // My 4 loads of stage t have landed (stage t+1's 4 may remain).
        if (t == NITER - 1) asm volatile("s_waitcnt vmcnt(0)" ::: "memory");
        else                asm volatile("s_waitcnt vmcnt(4)" ::: "memory");
        // Raw barrier (no drain): all waves' stage-t rows are in LDS and all
        // waves are done reading tile t-1.
        __builtin_amdgcn_s_barrier();
        if (t + 2 < NITER) stage(t + 2);   // overwrite buffer of tile t-1

        const int m = t % NBUF;
        float4 x[8];
#pragma unroll
        for (int r = 0; r < 8; ++r) x[r] = buf[m][r][col];

        if (set == 0) {
            int a = 0;
#pragma unroll
            for (int i = 0; i < MM; ++i)
#pragma unroll
                for (int j = i; j < MM; ++j) { acc[a] += dot4(x[i], x[j]); ++a; }
#pragma unroll
            for (int i = 0; i < 2; ++i)
#pragma unroll
                for (int j = 0; j < MM; ++j) { acc[a] += dot4(x[i], x[4 + j]); ++a; }
        } else {
            int a = 0;
#pragma unroll
            for (int i = 0; i < MM; ++i)
#pragma unroll
                for (int j = i; j < MM; ++j) { acc[a] += dot4(x[4 + i], x[4 + j]); ++a; }
#pragma unroll
            for (int i = 2; i < 4; ++i)
#pragma unroll
                for (int j = 0; j < MM; ++j) { acc[a] += dot4(x[i], x[4 + j]); ++a; }
        }
    }

    // 64-lane butterfly reduce (sums the 64 columns this wave covered).
#pragma unroll
    for (int k = 0; k < NPAIR; ++k) {
        float v = acc[k];
        for (int off = 32; off > 0; off >>= 1) v += __shfl_down(v, off, 64);
        acc[k] = v;
    }
    if (lane == 0) {
#pragma unroll
        for (int k = 0; k < NPAIR; ++k) red[wave][k] = acc[k];
    }
    __syncthreads();

    // Global pair order: k=0..9 ss, 10..19 rr, 20..35 cross (i-major).
    if (tid < NACC) {
        const int k = tid;
        float v;
        if (k < 10)       v = red[0][k]      + red[1][k];        // ss  (set A)
        else if (k < 20)  v = red[2][k - 10] + red[3][k - 10];   // rr  (set B)
        else if (k < 28)  v = red[0][10 + (k - 20)] + red[1][10 + (k - 20)]; // cross i=0,1
        else              v = red[2][10 + (k - 28)] + red[3][10 + (k - 28)]; // cross i=2,3
        partial[(size_t)blockIdx.x * NACC + k] = v;
    }
}

__global__ __launch_bounds__(1024) void mmd_final_kernel(
    const float* __restrict__ partial, const float* __restrict__ wt,
    const float* __restrict__ wtout, float* __restrict__ out)
{
    __shared__ float acc_s[NB][NACC];
    for (int p = threadIdx.x; p < NB * NACC; p += 1024) {
        const int b = p / NACC;
        const int k = p % NACC;
        float s = 0.0f;
        for (int blk = 0; blk < BPG; ++blk)
            s += partial[((size_t)b * BPG + blk) * NACC + k];
        acc_s[b][k] = s;
    }
    __syncthreads();

    __shared__ float lds[NB];
    const int b = threadIdx.x;
    if (b < NB) {
        const float* a = acc_s[b];
        float ss[MM][MM], rr[MM][MM], sg[MM][MM];
        {
            int k = 0;
            for (int i = 0; i < MM; ++i)
                for (int j = i; j < MM; ++j) { ss[i][j] = a[k]; ss[j][i] = a[k]; ++k; }
            for (int i = 0; i < MM; ++i)
                for (int j = i; j < MM; ++j) { rr[i][j] = a[k]; rr[j][i] = a[k]; ++k; }
            for (int i = 0; i < MM; ++i)
                for (int j = 0; j < MM; ++j) { sg[i][j] = a[k]; ++k; }
        }

        const float w    = wt[b];
        const float invD = 1.0f / (float)DD;  // sigma = 1
        auto kv = [&](float d2) -> float {
            d2 = fmaxf(d2, 1e-12f);
            float dist = sqrtf(d2) * invD;
            float e = -dist * w;
            e = fminf(fmaxf(e, -1e6f), 0.0f);
            return expf(e);
        };

        float mss = 0.0f, mrr = 0.0f, msr = 0.0f;
        for (int i = 0; i < MM; ++i) {
            for (int j = 0; j < MM; ++j) {
                mss += kv(ss[i][i] + ss[j][j] - 2.0f * ss[i][j]);
                mrr += kv(rr[i][i] + rr[j][j] - 2.0f * rr[i][j]);
                msr += kv(ss[i][i] + rr[j][j] - 2.0f * sg[i][j]);
            }
        }
        const float inv16 = 1.0f / 16.0f;
        float loss_raw = mss * inv16 + mrr * inv16 - 2.0f * (msr * inv16);
        lds[b] = wtout[b] * loss_raw;
    }
    __syncthreads();
    if (threadIdx.x == 0) {
        float s = 0.0f;
        for (int i = 0; i < NB; ++i) s += lds[i];
        out[0] = s / (float)NB;
    }
}

extern "C" void kernel_launch(void* const* d_in, const int* in_sizes, int n_in,
                              void* d_out, int out_size, void* d_ws, size_t ws_size,
                              hipStream_t stream) {
    const float* f_st  = (const float*)d_in[0];
    const float* f_sr  = (const float*)d_in[1];
    const float* wt    = (const float*)d_in[2];
    const float* wtout = (const float*)d_in[3];
    float* out     = (float*)d_out;
    float* partial = (float*)d_ws;   // NB*BPG*NACC floats = 110592 B

    mmd_partial_kernel<<<NB * BPG, NTHREADS, 0, stream>>>(f_st, f_sr, partial);
    mmd_final_kernel<<<1, 1024, 0, stream>>>(partial, wt, wtout, out);
}